// Round 1
// 113.034 us; speedup vs baseline: 1.1779x; 1.1779x over previous
//
#include <hip/hip_runtime.h>
#include <hip/hip_bf16.h>

#define DEV __device__ __forceinline__

typedef __bf16 bf16_t;
typedef bf16_t bf16x8 __attribute__((ext_vector_type(8)));
typedef float f32x4 __attribute__((ext_vector_type(4)));
typedef float f32x16 __attribute__((ext_vector_type(16)));
typedef unsigned int u32x4 __attribute__((ext_vector_type(4)));

constexpr int Bc = 2, Lc = 2048, Dc = 768, Hc = 12, HDc = 64;
constexpr int NTOK = Bc * Lc;     // 4096
constexpr int QKVN = 3 * Dc;      // 2304
constexpr float ATT_SCALE = 0.125f;          // 64^-0.5
constexpr float LOG2E = 1.44269504088896f;

DEV unsigned short f2bf(float f) {
  unsigned int u = __builtin_bit_cast(unsigned int, f);
  u += 0x7FFFu + ((u >> 16) & 1u);   // round-to-nearest-even
  return (unsigned short)(u >> 16);
}

DEV bf16x8 ld16(const unsigned short* p) {
  return __builtin_bit_cast(bf16x8, *reinterpret_cast<const u32x4*>(p));
}

DEV unsigned cvtpk(float lo, float hi) {
  unsigned r;
  asm("v_cvt_pk_bf16_f32 %0, %1, %2" : "=v"(r) : "v"(lo), "v"(hi));
  return r;
}

// async global->LDS, 16B per lane; lds dest = wave-uniform base + lane*16 (HW);
// global src address is PER-LANE (m173).
DEV void gload16(const unsigned short* g, unsigned short* l) {
  __builtin_amdgcn_global_load_lds(
      (const __attribute__((address_space(1))) unsigned int*)g,
      (__attribute__((address_space(3))) unsigned int*)l, 16, 0, 0);
}

// ---------------- fused prep: 3 bf16 converts + mask aux in ONE launch ----------------
// blocks [0,3072): x  [3072,4800): Wqkv  [4800,5376): Wout  [5376,5392): mask
__global__ __launch_bounds__(256) void prep_kernel(
    const float* __restrict__ x, const float* __restrict__ Wqkv,
    const float* __restrict__ Wout, const int* __restrict__ mask,
    unsigned short* __restrict__ xb, unsigned short* __restrict__ wqkvb,
    unsigned short* __restrict__ woutb, float* __restrict__ mb,
    int* __restrict__ mflag) {
  const int bid = blockIdx.x, tid = threadIdx.x;
  const float* src; unsigned short* dst; int base;
  if (bid < 3072)      { src = x;    dst = xb;    base = bid; }
  else if (bid < 4800) { src = Wqkv; dst = wqkvb; base = bid - 3072; }
  else if (bid < 5376) { src = Wout; dst = woutb; base = bid - 4800; }
  else {
    int i = (bid - 5376) * 256 + tid;
    int mv = mask[i];
    mb[i] = mv ? 0.f : -1e30f;
    unsigned long long anyz = __ballot(mv == 0);
    if ((tid & 63) == 0) mflag[i >> 6] = (anyz != 0ull) ? 1 : 0;
    return;
  }
  int i = (base * 256 + tid) * 4;
  float4 v = *reinterpret_cast<const float4*>(src + i);
  ushort4 o;
  o.x = f2bf(v.x); o.y = f2bf(v.y); o.z = f2bf(v.z); o.w = f2bf(v.w);
  *reinterpret_cast<ushort4*>(dst + i) = o;
}

// ---------------- bf16 GEMM (m97 structure), C[m,n] = sum_k A[m,k]*B[n,k] + bias[n] --------
// MODE 0: scatter to q/k/vT bf16 buffers (Q pre-scaled).  MODE 1: write f32 Y.
// MODE 0 epilogue (R11): V packed ushort4 along tokens ([bh][d][L] layout);
// Q/K via per-wave LDS patch -> full-128B-line vector stores (was 64 scalar 2B stores).
template <int MODE>
__global__ __launch_bounds__(256) void gemm_bt(
    const unsigned short* __restrict__ A,   // [M][K] bf16
    const unsigned short* __restrict__ Bw,  // [N][K] bf16
    const float* __restrict__ bias,         // [N]
    unsigned short* __restrict__ qb, unsigned short* __restrict__ kb,
    unsigned short* __restrict__ vtb,
    float* __restrict__ Y,
    int M, int N, int K) {
  constexpr int BM = 128, BN = 128, BK = 64;
  __shared__ alignas(16) unsigned short a_lds[BM * BK];  // linear [row][64]
  __shared__ alignas(16) unsigned short b_lds[BN * BK];
  __shared__ alignas(16) unsigned short qk_patch[(MODE == 0) ? 4 : 1][16][72];

  const int tid = threadIdx.x;
  const int lane = tid & 63;
  const int l15 = lane & 15, lg = lane >> 4;
  const int wave = tid >> 6;
  const int wr = wave >> 1, wc = wave & 1;

  const int ntiles = N / BN;
  const int m0 = (blockIdx.x / ntiles) * BM;
  const int n0 = (blockIdx.x % ntiles) * BN;

  f32x4 acc[4][4] = {};

  for (int k0 = 0; k0 < K; k0 += BK) {
#pragma unroll
    for (int i = 0; i < 4; ++i) {
      int cc = i * 256 + tid;            // this thread's chunk
      int row = cc >> 3, col = (cc & 7) * 8;
      gload16(A + (size_t)(m0 + row) * K + k0 + col, &a_lds[(i * 256 + wave * 64) * 8]);
      gload16(Bw + (size_t)(n0 + row) * K + k0 + col, &b_lds[(i * 256 + wave * 64) * 8]);
    }
    __syncthreads();
#pragma unroll
    for (int kk = 0; kk < 2; ++kk) {
      bf16x8 af[4], bfr[4];
#pragma unroll
      for (int m = 0; m < 4; ++m) {
        int row = wr * 64 + m * 16 + l15;
        af[m] = ld16(&a_lds[row * BK + kk * 32 + lg * 8]);
      }
#pragma unroll
      for (int n = 0; n < 4; ++n) {
        int row = wc * 64 + n * 16 + l15;
        bfr[n] = ld16(&b_lds[row * BK + kk * 32 + lg * 8]);
      }
#pragma unroll
      for (int m = 0; m < 4; ++m)
#pragma unroll
        for (int n = 0; n < 4; ++n)
          acc[m][n] = __builtin_amdgcn_mfma_f32_16x16x32_bf16(af[m], bfr[n], acc[m][n], 0, 0, 0);
    }
    __syncthreads();
  }

  // epilogue: C row = (lane>>4)*4 + j, col = lane&15 within each 16x16 tile
  if constexpr (MODE == 0) {
    // the wave's 64-col span = exactly one (s, head): N blocks of 128 | 768
    const int base_col = n0 + wc * 64;
    const int s = base_col / Dc;
    const int h = (base_col % Dc) >> 6;
    if (s == 2) {
      // V -> [bh][d][L]: pack 4 consecutive tokens (j) per store
#pragma unroll
      for (int m = 0; m < 4; ++m) {
        int lq = m0 + wr * 64 + m * 16 + lg * 4;
        int b = lq >> 11, lql = lq & 2047;
#pragma unroll
        for (int n = 0; n < 4; ++n) {
          int d = n * 16 + l15;
          float bv = bias[base_col + n * 16 + l15];
          ushort4 o;
#pragma unroll
          for (int j = 0; j < 4; ++j)
            ((unsigned short*)&o)[j] = f2bf(acc[m][n][j] + bv);
          *reinterpret_cast<ushort4*>(
              vtb + ((size_t)(b * Hc + h) * HDc + d) * Lc + lql) = o;
        }
      }
    } else {
      // Q/K -> [bh][L][64]: per-wave LDS patch, then full-line vector stores
      unsigned short* dst = (s == 0) ? qb : kb;
      const float sc = (s == 0) ? (ATT_SCALE * LOG2E) : 1.0f;
#pragma unroll
      for (int m = 0; m < 4; ++m) {
#pragma unroll
        for (int n = 0; n < 4; ++n) {
          float bv = bias[base_col + n * 16 + l15];
#pragma unroll
          for (int j = 0; j < 4; ++j)
            qk_patch[wave][lg * 4 + j][n * 16 + l15] =
                f2bf((acc[m][n][j] + bv) * sc);
        }
        // 16 rows x 64 cols = 128 chunks of 16B; 2 per lane; stores hit full 128B lines
#pragma unroll
        for (int i = 0; i < 2; ++i) {
          int task = i * 64 + lane;
          int r = task >> 3, ch = task & 7;
          int lq = m0 + wr * 64 + m * 16 + r;
          int b = lq >> 11, lql = lq & 2047;
          u32x4 v = *reinterpret_cast<const u32x4*>(&qk_patch[wave][r][ch * 8]);
          *reinterpret_cast<u32x4*>(
              dst + ((size_t)(b * Hc + h) * Lc + lql) * HDc + ch * 8) = v;
        }
      }
    }
  } else {
#pragma unroll
    for (int m = 0; m < 4; ++m) {
      int row_base = m0 + wr * 64 + m * 16 + lg * 4;
#pragma unroll
      for (int n = 0; n < 4; ++n) {
        int col = n0 + wc * 64 + n * 16 + l15;
        float bv = bias[col];
#pragma unroll
        for (int j = 0; j < 4; ++j)
          Y[(size_t)(row_base + j) * Dc + col] = acc[m][n][j] + bv;
      }
    }
  }
}

// ---------------- flash attention: LDS-shared K/V, 8 waves = 4 q-subtiles x 2 kv-halves ----
// Grid 384 = 8 XCD x 3 bh x 16 qblocks; 512 threads. Group g = wave>>2 sweeps kv half g
// (16 steps of 64); within a group the 4 waves share the group's staged K/V tile.
// No-running-max softmax: softmax(s)=2^s/Sum 2^s exact (scores bounded; masked -1e30 -> 0).
// Half-merge exact & trivial: O = (accO_g0+accO_g1)/(l_g0+l_g1), via dead k_lds.
// R12: K/V LDS tiles are row-major [64 rows][64 cols] with XOR swizzle
//   byte ^= (row&7)<<4 (m214 pattern). Staging is COALESCED: chunk j = 8 full
//   consecutive rows; lane l fetches row j*8+(l>>3), col-chunk (l&7)^(l>>3)
//   (inverse swizzle on the GLOBAL src, linear LDS dest — rule #21). The old
//   column-slice chunks forced 64 scattered 16B requests per global_load_lds.
__global__ __launch_bounds__(512) void attn_kernel(
    const unsigned short* __restrict__ qb,   // [BH][L][64], pre-scaled by SCALE*LOG2E
    const unsigned short* __restrict__ kb,   // [BH][L][64]
    const unsigned short* __restrict__ vtb,  // [BH][64][L] transposed
    const float* __restrict__ mb,            // [B][L]: 0 / -1e30
    const int* __restrict__ mflag,           // [B][L/64] any-masked flag
    unsigned short* __restrict__ aout) {     // [B][L][768]
  __shared__ alignas(16) unsigned short k_lds[2][2][4096];  // [group][buf][row*64+col^swz] 8KB
  __shared__ alignas(16) unsigned short v_lds[2][2][4096];
  __shared__ float l_lds[4][32];
  const int tid = threadIdx.x;
  const int lane = tid & 63;
  const int l31 = lane & 31;
  const int hi = lane >> 5;
  const int wave = tid >> 6;                 // 0..7
  const int g = wave >> 2;                   // kv half
  const int ws = wave & 3;                   // q sub-tile
  // XCD-clustered work assignment (384 = 8 XCD x 3 bh x 16 qblocks)
  const int f = blockIdx.x;
  const int loc = f >> 3;                    // 0..47
  const int bh = (f & 7) * 3 + (loc >> 4);
  const int b = bh / Hc, h = bh % Hc;
  const int q0 = (loc & 15) * 128 + ws * 32;
  const int kvbase = g * (Lc / 2);           // 0 or 1024

  const unsigned short* Kbh = kb + (size_t)bh * Lc * HDc;
  const unsigned short* Vbh = vtb + (size_t)bh * HDc * Lc;
  const float* mbb = mb + b * Lc + kvbase + hi * 4;
  const int* mfp = mflag + b * (Lc / 64) + (kvbase >> 6);

  // Q as B-operand: lane holds Q[q0+l31][c*16 + hi*8 + j]
  bf16x8 qf[4];
  {
    const unsigned short* Qp = qb + ((size_t)bh * Lc + q0 + l31) * HDc + hi * 8;
#pragma unroll
    for (int c = 0; c < 4; ++c) qf[c] = ld16(Qp + c * 16);
  }

  f32x16 accO[2] = {};   // O^T[d][q]: d = dt*32 + (reg&3)+8*(reg>>2)+4*hi, q = q0+l31
  float l_run = 0.f;

  // staging (coalesced): within group g, wave ws issues chunks j in {2ws,2ws+1};
  // chunk j = rows j*8..j*8+7 of the 64x64 tile, inverse-swizzled col order.
#define STAGE(buf, kv0abs)                                                            \
  {                                                                                   \
    _Pragma("unroll")                                                                 \
    for (int jj = 0; jj < 2; ++jj) {                                                  \
      int j = ws * 2 + jj;                                                            \
      int r8 = j * 8 + (lane >> 3);                                                   \
      int csw = ((lane & 7) ^ (lane >> 3)) << 3;                                      \
      gload16(Kbh + (size_t)((kv0abs) + r8) * HDc + csw, &k_lds[g][buf][j * 512]);    \
      gload16(Vbh + (size_t)r8 * Lc + (kv0abs) + csw, &v_lds[g][buf][j * 512]);       \
    }                                                                                 \
  }

  STAGE(0, kvbase)
  __syncthreads();   // drains vmcnt(0) -> buf0 ready

  const int swz = (l31 & 7) << 3;   // read-side XOR swizzle (same for rows r, r+32: bit5 unused)

  constexpr int NSTEP = Lc / 128;   // 16 per half
  for (int t = 0; t < NSTEP; ++t) {
    const int cur = t & 1;
    if (t + 1 < NSTEP) STAGE(cur ^ 1, kvbase + (t + 1) * 64)
    const unsigned short* kl = &k_lds[g][cur][0];
    const unsigned short* vl = &v_lds[g][cur][0];
    const int kv0 = t * 64;   // relative to kvbase

    // ---- S^T = K Q^T over 2 kv-tiles of 32 (K from LDS, swizzled rows, conflict-free) ----
    f32x16 s0 = {}, s1 = {};
    __builtin_amdgcn_s_setprio(1);
#pragma unroll
    for (int c = 0; c < 4; ++c) {
      int ch = (((c * 2 + hi) << 3) ^ swz);
      s0 = __builtin_amdgcn_mfma_f32_32x32x16_bf16(ld16(kl + l31 * 64 + ch), qf[c], s0, 0, 0, 0);
      s1 = __builtin_amdgcn_mfma_f32_32x32x16_bf16(ld16(kl + (32 + l31) * 64 + ch), qf[c], s1, 0, 0, 0);
    }
    __builtin_amdgcn_s_setprio(0);
    // ---- mask bias, in place (skip when tile has no masked tokens) ----
    if (mfp[t]) {
#pragma unroll
      for (int gg = 0; gg < 4; ++gg) {
        float4 m0v = *reinterpret_cast<const float4*>(mbb + kv0 + gg * 8);
        float4 m1v = *reinterpret_cast<const float4*>(mbb + kv0 + 32 + gg * 8);
        s0[gg * 4 + 0] += m0v.x; s0[gg * 4 + 1] += m0v.y;
        s0[gg * 4 + 2] += m0v.z; s0[gg * 4 + 3] += m0v.w;
        s1[gg * 4 + 0] += m1v.x; s1[gg * 4 + 1] += m1v.y;
        s1[gg * 4 + 2] += m1v.z; s1[gg * 4 + 3] += m1v.w;
      }
    }
    // ---- p = exp2(s) in place (raw v_exp_f32: no denorm guard needed; -1e30 -> 0) ----
    float rs0 = 0.f, rs1 = 0.f, rs2 = 0.f, rs3 = 0.f;
#pragma unroll
    for (int i = 0; i < 16; i += 4) {
      s0[i] = __builtin_amdgcn_exp2f(s0[i]);         rs0 += s0[i];
      s0[i + 1] = __builtin_amdgcn_exp2f(s0[i + 1]); rs1 += s0[i + 1];
      s0[i + 2] = __builtin_amdgcn_exp2f(s0[i + 2]); rs2 += s0[i + 2];
      s0[i + 3] = __builtin_amdgcn_exp2f(s0[i + 3]); rs3 += s0[i + 3];
      s1[i] = __builtin_amdgcn_exp2f(s1[i]);         rs0 += s1[i];
      s1[i + 1] = __builtin_amdgcn_exp2f(s1[i + 1]); rs1 += s1[i + 1];
      s1[i + 2] = __builtin_amdgcn_exp2f(s1[i + 2]); rs2 += s1[i + 2];
      s1[i + 3] = __builtin_amdgcn_exp2f(s1[i + 3]); rs3 += s1[i + 3];
    }
    float rs = (rs0 + rs1) + (rs2 + rs3);
    rs += __shfl_xor(rs, 32);
    l_run += rs;
    // ---- pack P -> PV B-frags: cvt_pk + permlane32_swap ----
    bf16x8 pf[4];
#pragma unroll
    for (int c = 0; c < 4; ++c) {
      const f32x16& sv = (c < 2) ? s0 : s1;
      const int o = (c & 1) * 8;
      unsigned pk01 = cvtpk(sv[o + 0], sv[o + 1]);
      unsigned pk23 = cvtpk(sv[o + 2], sv[o + 3]);
      unsigned pk45 = cvtpk(sv[o + 4], sv[o + 5]);
      unsigned pk67 = cvtpk(sv[o + 6], sv[o + 7]);
      asm("v_permlane32_swap_b32 %0, %1" : "+v"(pk01), "+v"(pk45));
      asm("v_permlane32_swap_b32 %0, %1" : "+v"(pk23), "+v"(pk67));
      u32x4 w = {pk01, pk23, pk45, pk67};
      pf[c] = __builtin_bit_cast(bf16x8, w);
    }
    // ---- O^T += V^T P^T (V from LDS, swizzled rows, conflict-free) ----
    __builtin_amdgcn_s_setprio(1);
#pragma unroll
    for (int dt = 0; dt < 2; ++dt) {
#pragma unroll
      for (int c = 0; c < 4; ++c) {
        int ch = (((c * 2 + hi) << 3) ^ swz);
        accO[dt] = __builtin_amdgcn_mfma_f32_32x32x16_bf16(ld16(vl + (dt * 32 + l31) * 64 + ch), pf[c], accO[dt], 0, 0, 0);
      }
    }
    __builtin_amdgcn_s_setprio(0);
    __syncthreads();   // buf[cur] fully consumed; next stage may overwrite
  }

  // ---- merge kv halves: group 1 publishes into dead k_lds, group 0 combines & writes ----
  float* mO = (float*)&k_lds[0][0][0];   // [ws][32][64] floats = 32KB, conflict-free lane-major
  if (g == 1) {
#pragma unroll
    for (int dt = 0; dt < 2; ++dt)
#pragma unroll
      for (int i = 0; i < 16; ++i)
        mO[(ws * 32 + dt * 16 + i) * 64 + lane] = accO[dt][i];
    if (hi == 0) l_lds[ws][l31] = l_run;
  }
  __syncthreads();
  if (g == 0) {
    float rl = 1.0f / (l_run + l_lds[ws][l31]);
    const int q = q0 + l31;
    unsigned short* op = aout + ((size_t)(b * Lc + q)) * Dc + h * HDc;
#pragma unroll
    for (int dt = 0; dt < 2; ++dt)
#pragma unroll
      for (int gg = 0; gg < 4; ++gg) {
        ushort4 o;
#pragma unroll
        for (int j = 0; j < 4; ++j) {
          int i = gg * 4 + j;
          float v = (accO[dt][i] + mO[(ws * 32 + dt * 16 + i) * 64 + lane]) * rl;
          ((unsigned short*)&o)[j] = f2bf(v);
        }
        *reinterpret_cast<ushort4*>(op + dt * 32 + gg * 8 + hi * 4) = o;
      }
  }
}

// ---------------- launch ----------------
extern "C" void kernel_launch(void* const* d_in, const int* in_sizes, int n_in,
                              void* d_out, int out_size, void* d_ws, size_t ws_size,
                              hipStream_t stream) {
  const float* x    = (const float*)d_in[0];
  const int*   mask = (const int*)d_in[1];
  const float* Wqkv = (const float*)d_in[2];
  const float* bqkv = (const float*)d_in[3];
  const float* Wout = (const float*)d_in[4];
  const float* bout = (const float*)d_in[5];
  float* out = (float*)d_out;

  constexpr size_t NX   = (size_t)NTOK * Dc;      // 3145728
  constexpr size_t NWQ  = (size_t)QKVN * Dc;      // 1769472
  constexpr size_t NWO  = (size_t)Dc * Dc;        // 589824
  unsigned short* w = (unsigned short*)d_ws;
  unsigned short* xb    = w;            w += NX;
  unsigned short* wqkvb = w;            w += NWQ;
  unsigned short* woutb = w;            w += NWO;
  unsigned short* qbuf  = w;            w += NX;
  unsigned short* kbuf  = w;            w += NX;
  unsigned short* vtb   = w;            w += NX;
  unsigned short* aoutb = w;            w += NX;
  float* mbf = (float*)w;               w += 2 * NTOK;
  int* mflag = (int*)w;

  // fused converts + mask aux (one launch instead of four)
  prep_kernel<<<5392, 256, 0, stream>>>(x, Wqkv, Wout, mask, xb, wqkvb, woutb, mbf, mflag);

  // QKV projection: M=4096, N=2304, K=768
  gemm_bt<0><<<(NTOK / 128) * (QKVN / 128), 256, 0, stream>>>(
      xb, wqkvb, bqkv, qbuf, kbuf, vtb, nullptr, NTOK, QKVN, Dc);

  // attention: 384 blocks x 512 threads (8 XCD x 3 bh x 16 qblocks; 4 q-subtiles x 2 kv-halves)
  attn_kernel<<<dim3(384), 512, 0, stream>>>(qbuf, kbuf, vtb, mbf, mflag, aoutb);

  // output projection: M=4096, N=768, K=768
  gemm_bt<1><<<(NTOK / 128) * (Dc / 128), 256, 0, stream>>>(
      aoutb, woutb, bout, nullptr, nullptr, nullptr, out, NTOK, Dc, Dc);
}